// Round 1
// baseline (1183.432 us; speedup 1.0000x reference)
//
#include <hip/hip_runtime.h>

#define B_  4
#define L_  8192
#define D_  512
#define H_  8
#define DK_ 64
#define F_  65      // DK + PD
#define CF_ 520     // H * F_
#define EPS_ 1e-5f

// ---------------- K1: projection GEMM ----------------
// C[m][n] = sum_k X[m][k] * W[n][k] + bias[n], written to concat layout:
// Out[m*520 + n + (n>>6) + 1]   (slot 0 of each 65-block reserved for pos)
#define K1_BM 128
#define K1_BN 128
#define K1_BK 16

__global__ __launch_bounds__(256)
void proj_gemm(const float* __restrict__ Xq, const float* __restrict__ Xk,
               const float* __restrict__ Xv,
               const float* __restrict__ Wq, const float* __restrict__ bq,
               const float* __restrict__ Wk, const float* __restrict__ bk,
               const float* __restrict__ Wv, const float* __restrict__ bv,
               float* __restrict__ Qc, float* __restrict__ Kc,
               float* __restrict__ Vc)
{
    const int z = blockIdx.z;
    const float* __restrict__ X    = (z == 0) ? Xq : (z == 1) ? Xk : Xv;
    const float* __restrict__ W    = (z == 0) ? Wq : (z == 1) ? Wk : Wv;
    const float* __restrict__ bias = (z == 0) ? bq : (z == 1) ? bk : bv;
    float* __restrict__ Out        = (z == 0) ? Qc : (z == 1) ? Kc : Vc;

    const int m0 = blockIdx.y * K1_BM;
    const int n0 = blockIdx.x * K1_BN;
    const int t  = threadIdx.x;
    const int tx = t & 15, ty = t >> 4;

    __shared__ __align__(16) float As[K1_BK][K1_BM + 4];
    __shared__ __align__(16) float Bs[K1_BK][K1_BN + 4];

    float acc[8][8];
#pragma unroll
    for (int i = 0; i < 8; ++i)
#pragma unroll
        for (int j = 0; j < 8; ++j) acc[i][j] = 0.0f;

    const int lr = t >> 2;            // 0..63
    const int lk = (t & 3) * 4;       // 0,4,8,12

    for (int k0 = 0; k0 < D_; k0 += K1_BK) {
        // A tile: rows m0..m0+127, k k0..k0+15
        {
            const float4 a0 = *(const float4*)&X[(size_t)(m0 + lr) * D_ + k0 + lk];
            const float4 a1 = *(const float4*)&X[(size_t)(m0 + lr + 64) * D_ + k0 + lk];
            As[lk + 0][lr] = a0.x; As[lk + 1][lr] = a0.y;
            As[lk + 2][lr] = a0.z; As[lk + 3][lr] = a0.w;
            As[lk + 0][lr + 64] = a1.x; As[lk + 1][lr + 64] = a1.y;
            As[lk + 2][lr + 64] = a1.z; As[lk + 3][lr + 64] = a1.w;
        }
        // B tile: W rows n0..n0+127 (note: C = X @ W^T so B[n][k] = W[n][k])
        {
            const float4 b0 = *(const float4*)&W[(size_t)(n0 + lr) * D_ + k0 + lk];
            const float4 b1 = *(const float4*)&W[(size_t)(n0 + lr + 64) * D_ + k0 + lk];
            Bs[lk + 0][lr] = b0.x; Bs[lk + 1][lr] = b0.y;
            Bs[lk + 2][lr] = b0.z; Bs[lk + 3][lr] = b0.w;
            Bs[lk + 0][lr + 64] = b1.x; Bs[lk + 1][lr + 64] = b1.y;
            Bs[lk + 2][lr + 64] = b1.z; Bs[lk + 3][lr + 64] = b1.w;
        }
        __syncthreads();
#pragma unroll
        for (int kk = 0; kk < K1_BK; ++kk) {
            const float4 a0 = *(const float4*)&As[kk][ty * 8];
            const float4 a1 = *(const float4*)&As[kk][ty * 8 + 4];
            const float4 b0 = *(const float4*)&Bs[kk][tx * 8];
            const float4 b1 = *(const float4*)&Bs[kk][tx * 8 + 4];
            const float av[8] = {a0.x, a0.y, a0.z, a0.w, a1.x, a1.y, a1.z, a1.w};
            const float bw[8] = {b0.x, b0.y, b0.z, b0.w, b1.x, b1.y, b1.z, b1.w};
#pragma unroll
            for (int i = 0; i < 8; ++i)
#pragma unroll
                for (int j = 0; j < 8; ++j)
                    acc[i][j] = fmaf(av[i], bw[j], acc[i][j]);
        }
        __syncthreads();
    }

    float bv_[8];
#pragma unroll
    for (int j = 0; j < 8; ++j) bv_[j] = bias[n0 + tx * 8 + j];

#pragma unroll
    for (int i = 0; i < 8; ++i) {
        const size_t m = (size_t)(m0 + ty * 8 + i);
#pragma unroll
        for (int j = 0; j < 8; ++j) {
            const int n = n0 + tx * 8 + j;
            const int h = n >> 6;
            Out[m * CF_ + n + h + 1] = acc[i][j] + bv_[j];
        }
    }
}

// ---------------- K2: per-head LayerNorm (K,V) + pos slots ----------------
__global__ __launch_bounds__(256)
void postproc(const float* __restrict__ pos,
              const float* __restrict__ gK, const float* __restrict__ betaK,
              const float* __restrict__ gV, const float* __restrict__ betaV,
              float* __restrict__ Qc, float* __restrict__ Kc,
              float* __restrict__ Vc)
{
    const int idx = blockIdx.x * 256 + threadIdx.x;  // 0 .. 32768*8-1
    const int m = idx >> 3;
    const int h = idx & 7;
    const float p = pos[m];
    const size_t base = (size_t)m * CF_ + h * F_;

    Qc[base] = p;

    float x[64];
    // ---- K ----
    {
        float s = 0.0f, sq = 0.0f;
#pragma unroll
        for (int c = 0; c < 64; ++c) {
            x[c] = Kc[base + 1 + c];
            s += x[c];
            sq = fmaf(x[c], x[c], sq);
        }
        const float mean = s * (1.0f / 64.0f);
        const float var = sq * (1.0f / 64.0f) - mean * mean;
        const float rs = rsqrtf(var + EPS_);
#pragma unroll
        for (int c = 0; c < 64; ++c) {
            Kc[base + 1 + c] = (x[c] - mean) * rs * gK[h * 64 + c] + betaK[h * 64 + c];
        }
        Kc[base] = p;
    }
    // ---- V ----
    {
        float s = 0.0f, sq = 0.0f;
#pragma unroll
        for (int c = 0; c < 64; ++c) {
            x[c] = Vc[base + 1 + c];
            s += x[c];
            sq = fmaf(x[c], x[c], sq);
        }
        const float mean = s * (1.0f / 64.0f);
        const float var = sq * (1.0f / 64.0f) - mean * mean;
        const float rs = rsqrtf(var + EPS_);
#pragma unroll
        for (int c = 0; c < 64; ++c) {
            Vc[base + 1 + c] = (x[c] - mean) * rs * gV[h * 64 + c] + betaV[h * 64 + c];
        }
        Vc[base] = p;
    }
}

// ---------------- K3: attn accumulation: sum_l K[l][d] * V[l][e] ----------------
__global__ __launch_bounds__(256)
void attn_accum(const float* __restrict__ Kc, const float* __restrict__ Vc,
                float* __restrict__ attn_acc)
{
    const int s = blockIdx.x;   // L slice 0..7
    const int h = blockIdx.y;
    const int b = blockIdx.z;
    const int t = threadIdx.x;

    __shared__ __align__(16) float Ks[64][68];
    __shared__ __align__(16) float Vs[64][68];

    float acc[4][4];
#pragma unroll
    for (int i = 0; i < 4; ++i)
#pragma unroll
        for (int j = 0; j < 4; ++j) acc[i][j] = 0.0f;

    const int d0 = (t >> 4) * 4;
    const int e0 = (t & 15) * 4;
    const bool hasE = (t < 129);
    int ed, ee;
    if (t < 65) { ed = 64; ee = t; } else { ed = t - 65; ee = 64; }
    float accE = 0.0f;

    for (int c = 0; c < 16; ++c) {
        const int l0 = s * 1024 + c * 64;
        for (int idx = t; idx < 64 * F_; idx += 256) {
            const int r = idx / F_;
            const int col = idx - r * F_;
            const size_t g = (size_t)(b * L_ + l0 + r) * CF_ + h * F_ + col;
            Ks[r][col] = Kc[g];
            Vs[r][col] = Vc[g];
        }
        __syncthreads();
#pragma unroll 4
        for (int l = 0; l < 64; ++l) {
            const float4 a = *(const float4*)&Ks[l][d0];
            const float4 v = *(const float4*)&Vs[l][e0];
            const float av[4] = {a.x, a.y, a.z, a.w};
            const float vv[4] = {v.x, v.y, v.z, v.w};
#pragma unroll
            for (int i = 0; i < 4; ++i)
#pragma unroll
                for (int j = 0; j < 4; ++j)
                    acc[i][j] = fmaf(av[i], vv[j], acc[i][j]);
            if (hasE) accE = fmaf(Ks[l][ed], Vs[l][ee], accE);
        }
        __syncthreads();
    }

    float* dst = attn_acc + (size_t)(b * H_ + h) * F_ * F_;
#pragma unroll
    for (int i = 0; i < 4; ++i)
#pragma unroll
        for (int j = 0; j < 4; ++j)
            atomicAdd(&dst[(d0 + i) * F_ + (e0 + j)], acc[i][j]);
    if (hasE) atomicAdd(&dst[ed * F_ + ee], accE);
}

// ---------------- K4: attn/L -> d_out, and G[b,h] = attn @ fcW_h^T ----------------
__global__ __launch_bounds__(256)
void attn_fin_G(const float* __restrict__ attn_acc, const float* __restrict__ fcW,
                float* __restrict__ attn_out, float* __restrict__ G)
{
    const int nc = blockIdx.x;  // n chunk 0..7 (64 each)
    const int h = blockIdx.y;
    const int b = blockIdx.z;
    const int t = threadIdx.x;

    __shared__ float S[F_][F_];
    __shared__ float Wl[64][F_];

    const float inv = 1.0f / (float)L_;
    const float* __restrict__ src = attn_acc + (size_t)(b * H_ + h) * F_ * F_;
    for (int idx = t; idx < F_ * F_; idx += 256) {
        const float v = src[idx] * inv;
        S[idx / F_][idx % F_] = v;
        if (nc == 0) attn_out[(size_t)(b * H_ + h) * F_ * F_ + idx] = v;
    }
    for (int idx = t; idx < 64 * F_; idx += 256) {
        const int j = idx / F_;
        const int e = idx - j * F_;
        Wl[j][e] = fcW[(size_t)(nc * 64 + j) * CF_ + h * F_ + e];
    }
    __syncthreads();

    for (int idx = t; idx < F_ * 64; idx += 256) {
        const int d = idx >> 6;
        const int j = idx & 63;
        float g = 0.0f;
#pragma unroll 5
        for (int e = 0; e < F_; ++e) g = fmaf(S[d][e], Wl[j][e], g);
        G[((size_t)(b * H_ + h) * F_ + d) * D_ + nc * 64 + j] = g;
    }
}

// ---------------- K5: att_output = Qcat_b @ Gcat_b + fcb ----------------
#define K5_BK 8
__global__ __launch_bounds__(256)
void out_gemm(const float* __restrict__ Qc, const float* __restrict__ G,
              const float* __restrict__ fcb, float* __restrict__ out)
{
    const int b = blockIdx.z;
    const int m0 = blockIdx.y * 128;
    const int n0 = blockIdx.x * 128;
    const int t = threadIdx.x;
    const int tx = t & 15, ty = t >> 4;

    __shared__ __align__(16) float As[K5_BK][132];
    __shared__ __align__(16) float Bs[K5_BK][132];

    float acc[8][8];
#pragma unroll
    for (int i = 0; i < 8; ++i)
#pragma unroll
        for (int j = 0; j < 8; ++j) acc[i][j] = 0.0f;

    const float* __restrict__ Ab = Qc + (size_t)b * L_ * CF_;
    const float* __restrict__ Bb = G + (size_t)b * CF_ * D_;

    const int ar = t >> 1;            // 0..127
    const int ak = (t & 1) * 4;       // 0,4
    const int bk = t >> 5;            // 0..7
    const int bc = (t & 31) * 4;      // 0..124

    for (int k0 = 0; k0 < CF_; k0 += K5_BK) {
        {
            const float4 a = *(const float4*)&Ab[(size_t)(m0 + ar) * CF_ + k0 + ak];
            As[ak + 0][ar] = a.x; As[ak + 1][ar] = a.y;
            As[ak + 2][ar] = a.z; As[ak + 3][ar] = a.w;
        }
        {
            const float4 v = *(const float4*)&Bb[(size_t)(k0 + bk) * D_ + n0 + bc];
            *(float4*)&Bs[bk][bc] = v;
        }
        __syncthreads();
#pragma unroll
        for (int kk = 0; kk < K5_BK; ++kk) {
            const float4 a0 = *(const float4*)&As[kk][ty * 8];
            const float4 a1 = *(const float4*)&As[kk][ty * 8 + 4];
            const float4 b0 = *(const float4*)&Bs[kk][tx * 8];
            const float4 b1 = *(const float4*)&Bs[kk][tx * 8 + 4];
            const float av[8] = {a0.x, a0.y, a0.z, a0.w, a1.x, a1.y, a1.z, a1.w};
            const float bw[8] = {b0.x, b0.y, b0.z, b0.w, b1.x, b1.y, b1.z, b1.w};
#pragma unroll
            for (int i = 0; i < 8; ++i)
#pragma unroll
                for (int j = 0; j < 8; ++j)
                    acc[i][j] = fmaf(av[i], bw[j], acc[i][j]);
        }
        __syncthreads();
    }

    float bias[8];
#pragma unroll
    for (int j = 0; j < 8; ++j) bias[j] = fcb[n0 + tx * 8 + j];

#pragma unroll
    for (int i = 0; i < 8; ++i) {
        const size_t row = (size_t)(b * L_ + m0 + ty * 8 + i) * D_ + n0 + tx * 8;
        float4 o0, o1;
        o0.x = acc[i][0] + bias[0]; o0.y = acc[i][1] + bias[1];
        o0.z = acc[i][2] + bias[2]; o0.w = acc[i][3] + bias[3];
        o1.x = acc[i][4] + bias[4]; o1.y = acc[i][5] + bias[5];
        o1.z = acc[i][6] + bias[6]; o1.w = acc[i][7] + bias[7];
        *(float4*)&out[row] = o0;
        *(float4*)&out[row + 4] = o1;
    }
}

extern "C" void kernel_launch(void* const* d_in, const int* in_sizes, int n_in,
                              void* d_out, int out_size, void* d_ws, size_t ws_size,
                              hipStream_t stream)
{
    const float* query = (const float*)d_in[0];
    const float* key   = (const float*)d_in[1];
    const float* value = (const float*)d_in[2];
    const float* pos   = (const float*)d_in[3];
    const float* Wq    = (const float*)d_in[4];
    const float* bq    = (const float*)d_in[5];
    const float* Wk    = (const float*)d_in[6];
    const float* bk    = (const float*)d_in[7];
    const float* Wv    = (const float*)d_in[8];
    const float* bv    = (const float*)d_in[9];
    const float* gK    = (const float*)d_in[10];
    const float* betaK = (const float*)d_in[11];
    const float* gV    = (const float*)d_in[12];
    const float* betaV = (const float*)d_in[13];
    const float* fcW   = (const float*)d_in[14];
    const float* fcb   = (const float*)d_in[15];

    float* ws = (float*)d_ws;
    float* Qc       = ws;                       // [32768][520]
    float* Kc       = ws + 17039360;            // [32768][520]
    float* Vc       = ws + 34078720;            // [32768][520]
    float* attn_acc = ws + 51118080;            // [4][8][65][65]
    float* G        = ws + 51253280;            // [4][520][512]

    float* att_out  = (float*)d_out;            // [4][8192][512]
    float* attn_out = att_out + 16777216;       // [4][8][65][65]

    hipMemsetAsync(attn_acc, 0, (size_t)135200 * sizeof(float), stream);

    proj_gemm<<<dim3(4, 256, 3), 256, 0, stream>>>(
        query, key, value, Wq, bq, Wk, bk, Wv, bv, Qc, Kc, Vc);

    postproc<<<dim3(1024), 256, 0, stream>>>(
        pos, gK, betaK, gV, betaV, Qc, Kc, Vc);

    attn_accum<<<dim3(8, 8, 4), 256, 0, stream>>>(Kc, Vc, attn_acc);

    attn_fin_G<<<dim3(8, 8, 4), 256, 0, stream>>>(attn_acc, fcW, attn_out, G);

    out_gemm<<<dim3(4, 64, 4), 256, 0, stream>>>(Qc, G, fcb, att_out);
}

// Round 2
// 614.992 us; speedup vs baseline: 1.9243x; 1.9243x over previous
//
#include <hip/hip_runtime.h>

typedef __attribute__((ext_vector_type(8))) short short8;
typedef __attribute__((ext_vector_type(4))) float f32x4;
typedef __attribute__((ext_vector_type(4))) unsigned short ushort4v;
typedef unsigned short ushort;
typedef unsigned int uint;

#define B_  4
#define L_  8192
#define D_  512
#define H_  8
#define F_  65      // DK + PD
#define CF_ 520     // H * F
#define CFP_ 544    // CF padded to multiple of 32 (MFMA K)
#define EPS_ 1e-5f

// fp32 -> bf16 round-to-nearest-even
__device__ __forceinline__ ushort f2b(float f) {
    uint x = __float_as_uint(f);
    uint r = (x + 0x7FFFu + ((x >> 16) & 1u)) >> 16;
    return (ushort)r;
}
__device__ __forceinline__ float b2f(ushort u) {
    return __uint_as_float(((uint)u) << 16);
}

#define GLD16(gptr, sptr) \
    __builtin_amdgcn_global_load_lds((const __attribute__((address_space(1))) void*)(gptr), \
                                     (__attribute__((address_space(3))) void*)(sptr), 16, 0, 0)

// ---------------- K0: cast Wq/Wk/Wv to bf16 ----------------
__global__ __launch_bounds__(256)
void cast_w(const float* __restrict__ Wq, const float* __restrict__ Wk,
            const float* __restrict__ Wv, ushort* __restrict__ Wb)
{
    const int i = blockIdx.x * 256 + threadIdx.x;      // 0..196607, 4 floats each
    const int z = i >> 16;                             // 65536 float4 per 512x512 matrix
    const float* __restrict__ src = (z == 0) ? Wq : (z == 1) ? Wk : Wv;
    const int o = (i & 65535) * 4;
    const float4 f = *(const float4*)&src[o];
    ushort4v v;
    v.x = f2b(f.x); v.y = f2b(f.y); v.z = f2b(f.z); v.w = f2b(f.w);
    *(ushort4v*)&Wb[(size_t)z * 262144 + o] = v;
}

// ---------------- K1: MFMA projection GEMM (bf16) ----------------
// C[m][n] = sum_k X[m][k]*W[n][k] + bias[n], bf16 output in concat layout:
// col = n + (n>>6) + 1 (slot h*65 reserved for pos), row stride 544 (Q) / 520 (K,V)
__global__ __launch_bounds__(256, 2)
void proj_mfma(const float* __restrict__ Xq, const float* __restrict__ Xk,
               const float* __restrict__ Xv, const ushort* __restrict__ Wb,
               const float* __restrict__ bq, const float* __restrict__ bk,
               const float* __restrict__ bv,
               ushort* __restrict__ Qc, ushort* __restrict__ Kc,
               ushort* __restrict__ Vc)
{
    const int z = blockIdx.z;
    const float*  __restrict__ X    = (z == 0) ? Xq : (z == 1) ? Xk : Xv;
    const ushort* __restrict__ W    = Wb + (size_t)z * 262144;
    const float*  __restrict__ bias = (z == 0) ? bq : (z == 1) ? bk : bv;
    ushort* __restrict__ Out        = (z == 0) ? Qc : (z == 1) ? Kc : Vc;
    const int ostride = (z == 0) ? CFP_ : CF_;

    const int m0 = blockIdx.y * 128;
    const int n0 = blockIdx.x * 128;
    const int t  = threadIdx.x;
    const int w  = t >> 6, l = t & 63;
    const int wm = (w >> 1) * 64, wn = (w & 1) * 64;
    const int lg = l >> 4, lm = l & 15;

    // LDS layout: slot s (16B) holds 8 bf16; A slot(g,m) = g*128+m holds
    // X[m0+m][k0+8g .. +7]; B slot(g,n) holds W[n0+n][k0+8g .. +7]
    __shared__ __align__(16) short sA[4096];
    __shared__ __align__(16) short sB[4096];

    f32x4 acc[4][4];
#pragma unroll
    for (int i = 0; i < 4; ++i)
#pragma unroll
        for (int j = 0; j < 4; ++j) acc[i][j] = (f32x4){0.f, 0.f, 0.f, 0.f};

    // A staging (fp32 -> bf16 via VALU): thread covers row m=t>>1, 16 k at (t&1)*16
    const int am = t >> 1;
    const int ag = (t & 1) * 2;
    const float* aptr = &X[(size_t)(m0 + am) * D_ + (t & 1) * 16];
    short* aw0 = &sA[(ag * 128 + am) * 8];
    short* aw1 = &sA[((ag + 1) * 128 + am) * 8];

    // B staging via global_load_lds: wave w covers g=w; 2 instrs cover n=0..127
    const ushort* bsrc0 = &W[(size_t)(n0 + l) * D_ + w * 8];
    const ushort* bsrc1 = &W[(size_t)(n0 + 64 + l) * D_ + w * 8];
    short* bl0 = &sB[(w * 128) * 8];
    short* bl1 = &sB[(w * 128 + 64) * 8];

    // fragment read pointers (lane-linear within 16-lane groups)
    const short* ar[4]; const short* br[4];
#pragma unroll
    for (int i = 0; i < 4; ++i) {
        ar[i] = &sA[(lg * 128 + wm + i * 16 + lm) * 8];
        br[i] = &sB[(lg * 128 + wn + i * 16 + lm) * 8];
    }

    for (int k0 = 0; k0 < D_; k0 += 32) {
        const float4 f0 = *(const float4*)(aptr + k0);
        const float4 f1 = *(const float4*)(aptr + k0 + 4);
        const float4 f2 = *(const float4*)(aptr + k0 + 8);
        const float4 f3 = *(const float4*)(aptr + k0 + 12);
        short8 v0, v1;
        v0[0] = (short)f2b(f0.x); v0[1] = (short)f2b(f0.y);
        v0[2] = (short)f2b(f0.z); v0[3] = (short)f2b(f0.w);
        v0[4] = (short)f2b(f1.x); v0[5] = (short)f2b(f1.y);
        v0[6] = (short)f2b(f1.z); v0[7] = (short)f2b(f1.w);
        v1[0] = (short)f2b(f2.x); v1[1] = (short)f2b(f2.y);
        v1[2] = (short)f2b(f2.z); v1[3] = (short)f2b(f2.w);
        v1[4] = (short)f2b(f3.x); v1[5] = (short)f2b(f3.y);
        v1[6] = (short)f2b(f3.z); v1[7] = (short)f2b(f3.w);
        *(short8*)aw0 = v0;
        *(short8*)aw1 = v1;

        GLD16(bsrc0 + k0, bl0);
        GLD16(bsrc1 + k0, bl1);

        __syncthreads();

        short8 af[4], bfv[4];
#pragma unroll
        for (int i = 0; i < 4; ++i) {
            af[i]  = *(const short8*)ar[i];
            bfv[i] = *(const short8*)br[i];
        }
#pragma unroll
        for (int mt = 0; mt < 4; ++mt)
#pragma unroll
            for (int nt = 0; nt < 4; ++nt)
                acc[mt][nt] = __builtin_amdgcn_mfma_f32_16x16x32_bf16(
                    af[mt], bfv[nt], acc[mt][nt], 0, 0, 0);

        __syncthreads();
    }

    float bvv[4];
#pragma unroll
    for (int nt = 0; nt < 4; ++nt) bvv[nt] = bias[n0 + wn + nt * 16 + lm];

#pragma unroll
    for (int mt = 0; mt < 4; ++mt) {
#pragma unroll
        for (int r = 0; r < 4; ++r) {
            const int row = m0 + wm + mt * 16 + lg * 4 + r;
            ushort* orow = Out + (size_t)row * ostride;
#pragma unroll
            for (int nt = 0; nt < 4; ++nt) {
                const int n = n0 + wn + nt * 16 + lm;
                orow[n + (n >> 6) + 1] = f2b(acc[mt][nt][r] + bvv[nt]);
            }
        }
    }
}

// ---------------- K2: per-head LayerNorm (bf16 in/out) + pos slots + Q pad ----------------
__global__ __launch_bounds__(256)
void postproc(const float* __restrict__ pos,
              const float* __restrict__ gK, const float* __restrict__ betaK,
              const float* __restrict__ gV, const float* __restrict__ betaV,
              ushort* __restrict__ Qc, ushort* __restrict__ Kc,
              ushort* __restrict__ Vc)
{
    const int idx = blockIdx.x * 256 + threadIdx.x;   // 0 .. 32768*8-1
    const int m = idx >> 3;
    const int h = idx & 7;
    const float p = pos[m];
    const ushort pb = f2b(p);

    Qc[(size_t)m * CFP_ + h * F_] = pb;
    if (h == 7) {
        ushort* q = &Qc[(size_t)m * CFP_ + CF_];
#pragma unroll
        for (int c = 0; c < 24; ++c) q[c] = 0;
    }

    float x[64];
    // ---- K ----
    {
        ushort* row = &Kc[(size_t)m * CF_ + h * F_];
        float s = 0.f, sq = 0.f;
#pragma unroll
        for (int c = 0; c < 64; ++c) {
            x[c] = b2f(row[1 + c]);
            s += x[c];
            sq = fmaf(x[c], x[c], sq);
        }
        const float mean = s * (1.f / 64.f);
        const float var = sq * (1.f / 64.f) - mean * mean;
        const float rs = rsqrtf(var + EPS_);
#pragma unroll
        for (int c = 0; c < 64; ++c)
            row[1 + c] = f2b((x[c] - mean) * rs * gK[h * 64 + c] + betaK[h * 64 + c]);
        row[0] = pb;
    }
    // ---- V ----
    {
        ushort* row = &Vc[(size_t)m * CF_ + h * F_];
        float s = 0.f, sq = 0.f;
#pragma unroll
        for (int c = 0; c < 64; ++c) {
            x[c] = b2f(row[1 + c]);
            s += x[c];
            sq = fmaf(x[c], x[c], sq);
        }
        const float mean = s * (1.f / 64.f);
        const float var = sq * (1.f / 64.f) - mean * mean;
        const float rs = rsqrtf(var + EPS_);
#pragma unroll
        for (int c = 0; c < 64; ++c)
            row[1 + c] = f2b((x[c] - mean) * rs * gV[h * 64 + c] + betaV[h * 64 + c]);
        row[0] = pb;
    }
}

// ---------------- K3: attn accumulation: sum_l K[l][d]*V[l][e] ----------------
__global__ __launch_bounds__(256)
void attn_accum(const ushort* __restrict__ Kc, const ushort* __restrict__ Vc,
                float* __restrict__ attn_acc)
{
    const int s = blockIdx.x;   // L slice 0..31 (256 rows each)
    const int h = blockIdx.y;
    const int b = blockIdx.z;
    const int t = threadIdx.x;

    __shared__ __align__(16) float Ks[64][68];
    __shared__ __align__(16) float Vs[64][68];

    float acc[4][4];
#pragma unroll
    for (int i = 0; i < 4; ++i)
#pragma unroll
        for (int j = 0; j < 4; ++j) acc[i][j] = 0.f;

    const int d0 = (t >> 4) * 4;
    const int e0 = (t & 15) * 4;
    const bool hasE = (t < 129);
    int ed, ee;
    if (t < 65) { ed = 64; ee = t; } else { ed = t - 65; ee = 64; }
    float accE = 0.f;

    for (int c = 0; c < 4; ++c) {
        const int l0 = s * 256 + c * 64;
        for (int idx = t; idx < 64 * F_; idx += 256) {
            const int r = idx / F_;
            const int col = idx - r * F_;
            const size_t g = (size_t)(b * L_ + l0 + r) * CF_ + h * F_ + col;
            Ks[r][col] = b2f(Kc[g]);
            Vs[r][col] = b2f(Vc[g]);
        }
        __syncthreads();
#pragma unroll 4
        for (int l = 0; l < 64; ++l) {
            const float4 a = *(const float4*)&Ks[l][d0];
            const float4 v = *(const float4*)&Vs[l][e0];
            const float av[4] = {a.x, a.y, a.z, a.w};
            const float vv[4] = {v.x, v.y, v.z, v.w};
#pragma unroll
            for (int i = 0; i < 4; ++i)
#pragma unroll
                for (int j = 0; j < 4; ++j)
                    acc[i][j] = fmaf(av[i], vv[j], acc[i][j]);
            if (hasE) accE = fmaf(Ks[l][ed], Vs[l][ee], accE);
        }
        __syncthreads();
    }

    float* dst = attn_acc + (size_t)(b * H_ + h) * F_ * F_;
#pragma unroll
    for (int i = 0; i < 4; ++i)
#pragma unroll
        for (int j = 0; j < 4; ++j)
            atomicAdd(&dst[(d0 + i) * F_ + (e0 + j)], acc[i][j]);
    if (hasE) atomicAdd(&dst[ed * F_ + ee], accE);
}

// ---------------- K4: attn/L -> d_out; Gt[b][n][k] = (attn @ fcW_h^T)^T in bf16 ----------------
__global__ __launch_bounds__(256)
void attn_fin_G(const float* __restrict__ attn_acc, const float* __restrict__ fcW,
                float* __restrict__ attn_out, ushort* __restrict__ Gt)
{
    const int nc = blockIdx.x;  // n chunk 0..7 (64 each)
    const int h = blockIdx.y;
    const int b = blockIdx.z;
    const int t = threadIdx.x;

    __shared__ float S[F_][F_];
    __shared__ float Wl[64][F_];

    const float inv = 1.0f / (float)L_;
    const float* __restrict__ src = attn_acc + (size_t)(b * H_ + h) * F_ * F_;
    for (int idx = t; idx < F_ * F_; idx += 256) {
        const float v = src[idx] * inv;
        S[idx / F_][idx % F_] = v;
        if (nc == 0) attn_out[(size_t)(b * H_ + h) * F_ * F_ + idx] = v;
    }
    for (int idx = t; idx < 64 * F_; idx += 256) {
        const int j = idx / F_;
        const int e = idx - j * F_;
        Wl[j][e] = fcW[(size_t)(nc * 64 + j) * CF_ + h * F_ + e];
    }
    __syncthreads();

    for (int idx = t; idx < F_ * 64; idx += 256) {
        const int d = idx >> 6;
        const int j = idx & 63;
        float g = 0.f;
#pragma unroll 5
        for (int e = 0; e < F_; ++e) g = fmaf(S[d][e], Wl[j][e], g);
        Gt[((size_t)b * 512 + nc * 64 + j) * CFP_ + h * F_ + d] = f2b(g);
    }
    if (h == 7) {
        for (int i2 = t; i2 < 64 * 24; i2 += 256) {
            const int j = i2 / 24;
            const int k = CF_ + (i2 % 24);
            Gt[((size_t)b * 512 + nc * 64 + j) * CFP_ + k] = 0;
        }
    }
}

// ---------------- K5: att_output = Qc @ Gt^T + fcb  (bf16 MFMA, fp32 out) ----------------
__global__ __launch_bounds__(256, 2)
void out_mfma(const ushort* __restrict__ Qc, const ushort* __restrict__ Gt,
              const float* __restrict__ fcb, float* __restrict__ out)
{
    const int b  = blockIdx.z;
    const int m0 = blockIdx.y * 128;
    const int n0 = blockIdx.x * 128;
    const int t  = threadIdx.x;
    const int w  = t >> 6, l = t & 63;
    const int wm = (w >> 1) * 64, wn = (w & 1) * 64;
    const int lg = l >> 4, lm = l & 15;

    __shared__ __align__(16) short sA[4096];
    __shared__ __align__(16) short sB[4096];

    f32x4 acc[4][4];
#pragma unroll
    for (int i = 0; i < 4; ++i)
#pragma unroll
        for (int j = 0; j < 4; ++j) acc[i][j] = (f32x4){0.f, 0.f, 0.f, 0.f};

    const ushort* A  = Qc + (size_t)(b * L_ + m0) * CFP_;
    const ushort* Bm = Gt + ((size_t)b * 512 + n0) * CFP_;

    const ushort* asrc0 = A + (size_t)l * CFP_ + w * 8;
    const ushort* asrc1 = A + (size_t)(64 + l) * CFP_ + w * 8;
    const ushort* bsrc0 = Bm + (size_t)l * CFP_ + w * 8;
    const ushort* bsrc1 = Bm + (size_t)(64 + l) * CFP_ + w * 8;
    short* al0 = &sA[(w * 128) * 8];
    short* al1 = &sA[(w * 128 + 64) * 8];
    short* bl0 = &sB[(w * 128) * 8];
    short* bl1 = &sB[(w * 128 + 64) * 8];

    const short* ar[4]; const short* br[4];
#pragma unroll
    for (int i = 0; i < 4; ++i) {
        ar[i] = &sA[(lg * 128 + wm + i * 16 + lm) * 8];
        br[i] = &sB[(lg * 128 + wn + i * 16 + lm) * 8];
    }

    for (int k0 = 0; k0 < CFP_; k0 += 32) {
        GLD16(asrc0 + k0, al0);
        GLD16(asrc1 + k0, al1);
        GLD16(bsrc0 + k0, bl0);
        GLD16(bsrc1 + k0, bl1);

        __syncthreads();

        short8 af[4], bfv[4];
#pragma unroll
        for (int i = 0; i < 4; ++i) {
            af[i]  = *(const short8*)ar[i];
            bfv[i] = *(const short8*)br[i];
        }
#pragma unroll
        for (int mt = 0; mt < 4; ++mt)
#pragma unroll
            for (int nt = 0; nt < 4; ++nt)
                acc[mt][nt] = __builtin_amdgcn_mfma_f32_16x16x32_bf16(
                    af[mt], bfv[nt], acc[mt][nt], 0, 0, 0);

        __syncthreads();
    }

    float bvv[4];
#pragma unroll
    for (int nt = 0; nt < 4; ++nt) bvv[nt] = fcb[n0 + wn + nt * 16 + lm];

#pragma unroll
    for (int mt = 0; mt < 4; ++mt) {
#pragma unroll
        for (int r = 0; r < 4; ++r) {
            const int row = m0 + wm + mt * 16 + lg * 4 + r;
            float* orow = out + ((size_t)b * L_ + row) * D_;
#pragma unroll
            for (int nt = 0; nt < 4; ++nt)
                orow[n0 + wn + nt * 16 + lm] = acc[mt][nt][r] + bvv[nt];
        }
    }
}

extern "C" void kernel_launch(void* const* d_in, const int* in_sizes, int n_in,
                              void* d_out, int out_size, void* d_ws, size_t ws_size,
                              hipStream_t stream)
{
    const float* query = (const float*)d_in[0];
    const float* key   = (const float*)d_in[1];
    const float* value = (const float*)d_in[2];
    const float* pos   = (const float*)d_in[3];
    const float* Wq    = (const float*)d_in[4];
    const float* bq    = (const float*)d_in[5];
    const float* Wk    = (const float*)d_in[6];
    const float* bk    = (const float*)d_in[7];
    const float* Wv    = (const float*)d_in[8];
    const float* bv    = (const float*)d_in[9];
    const float* gK    = (const float*)d_in[10];
    const float* betaK = (const float*)d_in[11];
    const float* gV    = (const float*)d_in[12];
    const float* betaV = (const float*)d_in[13];
    const float* fcW   = (const float*)d_in[14];
    const float* fcb   = (const float*)d_in[15];

    char* ws = (char*)d_ws;
    ushort* Qc       = (ushort*)(ws + 0);          // [32768][544] bf16
    ushort* Kc       = (ushort*)(ws + 35651584);   // [32768][520] bf16
    ushort* Vc       = (ushort*)(ws + 69730304);   // [32768][520] bf16
    ushort* Wb       = (ushort*)(ws + 103809024);  // [3][512][512] bf16
    float*  attn_acc = (float*) (ws + 105381888);  // [4][8][65][65] fp32
    ushort* Gt       = (ushort*)(ws + 105922816);  // [4][512][544] bf16

    float* att_out  = (float*)d_out;               // [4][8192][512]
    float* attn_out = att_out + 16777216;          // [4][8][65][65]

    hipMemsetAsync(attn_acc, 0, (size_t)135200 * sizeof(float), stream);

    cast_w<<<dim3(768), 256, 0, stream>>>(Wq, Wk, Wv, Wb);

    proj_mfma<<<dim3(4, 256, 3), 256, 0, stream>>>(
        query, key, value, Wb, bq, bk, bv, Qc, Kc, Vc);

    postproc<<<dim3(1024), 256, 0, stream>>>(
        pos, gK, betaK, gV, betaV, Qc, Kc, Vc);

    attn_accum<<<dim3(32, 8, 4), 256, 0, stream>>>(Kc, Vc, attn_acc);

    attn_fin_G<<<dim3(8, 8, 4), 256, 0, stream>>>(attn_acc, fcW, attn_out, Gt);

    out_mfma<<<dim3(4, 64, 4), 256, 0, stream>>>(Qc, Gt, fcb, att_out);
}

// Round 3
// 514.877 us; speedup vs baseline: 2.2985x; 1.1944x over previous
//
#include <hip/hip_runtime.h>

typedef __attribute__((ext_vector_type(8))) short short8;
typedef __attribute__((ext_vector_type(4))) float f32x4;
typedef __attribute__((ext_vector_type(4))) unsigned short ushort4v;
typedef unsigned short ushort;
typedef unsigned int uint;

#define B_  4
#define L_  8192
#define D_  512
#define H_  8
#define F_  65      // DK + PD
#define CF_ 520     // H * F
#define CFP_ 544    // CF padded to multiple of 32 (MFMA K)
#define KVS_ 80     // K/V head-major row stride (65 used + 15 pad)
#define EPS_ 1e-5f

// fp32 -> bf16 round-to-nearest-even
__device__ __forceinline__ ushort f2b(float f) {
    uint x = __float_as_uint(f);
    uint r = (x + 0x7FFFu + ((x >> 16) & 1u)) >> 16;
    return (ushort)r;
}
__device__ __forceinline__ float b2f(ushort u) {
    return __uint_as_float(((uint)u) << 16);
}

#define GLD16(gptr, sptr) \
    __builtin_amdgcn_global_load_lds((const __attribute__((address_space(1))) void*)(gptr), \
                                     (__attribute__((address_space(3))) void*)(sptr), 16, 0, 0)

// ---------------- K0: cast Wq/Wk/Wv to bf16 ----------------
__global__ __launch_bounds__(256)
void cast_w(const float* __restrict__ Wq, const float* __restrict__ Wk,
            const float* __restrict__ Wv, ushort* __restrict__ Wb)
{
    const int i = blockIdx.x * 256 + threadIdx.x;
    const int z = i >> 16;
    const float* __restrict__ src = (z == 0) ? Wq : (z == 1) ? Wk : Wv;
    const int o = (i & 65535) * 4;
    const float4 f = *(const float4*)&src[o];
    ushort4v v;
    v.x = f2b(f.x); v.y = f2b(f.y); v.z = f2b(f.z); v.w = f2b(f.w);
    *(ushort4v*)&Wb[(size_t)z * 262144 + o] = v;
}

// ---------------- K1: MFMA projection GEMM + fused LN/pos epilogue ----------------
// z=0: Qc[m][544] concat layout (pos slots + zero pad 520..543)
// z=1: Kh[b][h][l][80] = [pos, LN(k), 0...]; z=2: Vh likewise.
__global__ __launch_bounds__(256, 2)
void proj_mfma(const float* __restrict__ Xq, const float* __restrict__ Xk,
               const float* __restrict__ Xv, const ushort* __restrict__ Wb,
               const float* __restrict__ bq, const float* __restrict__ bk,
               const float* __restrict__ bv, const float* __restrict__ pos,
               const float* __restrict__ gK, const float* __restrict__ betaK,
               const float* __restrict__ gV, const float* __restrict__ betaV,
               ushort* __restrict__ Qc, ushort* __restrict__ Kh,
               ushort* __restrict__ Vh)
{
    const int x  = blockIdx.x;
    const int m0 = (((x >> 5) << 3) + (x & 7)) * 128;   // XCD swizzle: same-m n-tiles
    const int n0 = ((x >> 3) & 3) * 128;                // land on same XCD, ids 8 apart
    const int z  = blockIdx.y;

    const float*  __restrict__ X    = (z == 0) ? Xq : (z == 1) ? Xk : Xv;
    const ushort* __restrict__ W    = Wb + (size_t)z * 262144;
    const float*  __restrict__ bias = (z == 0) ? bq : (z == 1) ? bk : bv;

    const int t  = threadIdx.x;
    const int w  = t >> 6, l = t & 63;
    const int wm = (w >> 1) * 64, wn = (w & 1) * 64;
    const int lg = l >> 4, lm = l & 15;

    __shared__ __align__(16) short sA[4096];
    __shared__ __align__(16) short sB[4096];

    f32x4 acc[4][4];
#pragma unroll
    for (int i = 0; i < 4; ++i)
#pragma unroll
        for (int j = 0; j < 4; ++j) acc[i][j] = (f32x4){0.f, 0.f, 0.f, 0.f};

    const int am = t >> 1;
    const int ag = (t & 1) * 2;
    const float* aptr = &X[(size_t)(m0 + am) * D_ + (t & 1) * 16];
    short* aw0 = &sA[(ag * 128 + am) * 8];
    short* aw1 = &sA[((ag + 1) * 128 + am) * 8];

    const ushort* bsrc0 = &W[(size_t)(n0 + l) * D_ + w * 8];
    const ushort* bsrc1 = &W[(size_t)(n0 + 64 + l) * D_ + w * 8];
    short* bl0 = &sB[(w * 128) * 8];
    short* bl1 = &sB[(w * 128 + 64) * 8];

    const short* ar[4]; const short* br[4];
#pragma unroll
    for (int i = 0; i < 4; ++i) {
        ar[i] = &sA[(lg * 128 + wm + i * 16 + lm) * 8];
        br[i] = &sB[(lg * 128 + wn + i * 16 + lm) * 8];
    }

    for (int k0 = 0; k0 < D_; k0 += 32) {
        const float4 f0 = *(const float4*)(aptr + k0);
        const float4 f1 = *(const float4*)(aptr + k0 + 4);
        const float4 f2 = *(const float4*)(aptr + k0 + 8);
        const float4 f3 = *(const float4*)(aptr + k0 + 12);
        short8 v0, v1;
        v0[0] = (short)f2b(f0.x); v0[1] = (short)f2b(f0.y);
        v0[2] = (short)f2b(f0.z); v0[3] = (short)f2b(f0.w);
        v0[4] = (short)f2b(f1.x); v0[5] = (short)f2b(f1.y);
        v0[6] = (short)f2b(f1.z); v0[7] = (short)f2b(f1.w);
        v1[0] = (short)f2b(f2.x); v1[1] = (short)f2b(f2.y);
        v1[2] = (short)f2b(f2.z); v1[3] = (short)f2b(f2.w);
        v1[4] = (short)f2b(f3.x); v1[5] = (short)f2b(f3.y);
        v1[6] = (short)f2b(f3.z); v1[7] = (short)f2b(f3.w);
        *(short8*)aw0 = v0;
        *(short8*)aw1 = v1;

        GLD16(bsrc0 + k0, bl0);
        GLD16(bsrc1 + k0, bl1);

        __syncthreads();

        short8 af[4], bfv[4];
#pragma unroll
        for (int i = 0; i < 4; ++i) {
            af[i]  = *(const short8*)ar[i];
            bfv[i] = *(const short8*)br[i];
        }
#pragma unroll
        for (int mt = 0; mt < 4; ++mt)
#pragma unroll
            for (int nt = 0; nt < 4; ++nt)
                acc[mt][nt] = __builtin_amdgcn_mfma_f32_16x16x32_bf16(
                    af[mt], bfv[nt], acc[mt][nt], 0, 0, 0);

        __syncthreads();
    }

    // -------- fused epilogue --------
    const int h = (n0 >> 6) + (w & 1);   // this wave's head (wave owns 64 rows x 64 head-cols)
    float bvv[4];
#pragma unroll
    for (int nt = 0; nt < 4; ++nt) bvv[nt] = bias[n0 + wn + nt * 16 + lm];

    if (z == 0) {
#pragma unroll
        for (int mt = 0; mt < 4; ++mt) {
#pragma unroll
            for (int r = 0; r < 4; ++r) {
                const int m = m0 + wm + mt * 16 + lg * 4 + r;
                ushort* orow = Qc + (size_t)m * CFP_ + h * F_;
#pragma unroll
                for (int nt = 0; nt < 4; ++nt)
                    orow[1 + nt * 16 + lm] = f2b(acc[mt][nt][r] + bvv[nt]);
                if (lm == 15) orow[0] = f2b(pos[m]);
                if (h == 7 && lm < 12) *(uint*)&Qc[(size_t)m * CFP_ + CF_ + 2 * lm] = 0u;
            }
        }
    } else {
        const float* gp = (z == 1) ? gK : gV;
        const float* bp = (z == 1) ? betaK : betaV;
        ushort* Oh = (z == 1) ? Kh : Vh;
        float gg[4], bb2[4];
#pragma unroll
        for (int nt = 0; nt < 4; ++nt) {
            gg[nt]  = gp[h * 64 + nt * 16 + lm];
            bb2[nt] = bp[h * 64 + nt * 16 + lm];
        }
#pragma unroll
        for (int mt = 0; mt < 4; ++mt) {
#pragma unroll
            for (int r = 0; r < 4; ++r) {
                float v0 = acc[mt][0][r] + bvv[0];
                float v1 = acc[mt][1][r] + bvv[1];
                float v2 = acc[mt][2][r] + bvv[2];
                float v3 = acc[mt][3][r] + bvv[3];
                float s = v0 + v1 + v2 + v3;
                float q = v0 * v0 + v1 * v1 + v2 * v2 + v3 * v3;
                s += __shfl_xor(s, 1); s += __shfl_xor(s, 2);
                s += __shfl_xor(s, 4); s += __shfl_xor(s, 8);
                q += __shfl_xor(q, 1); q += __shfl_xor(q, 2);
                q += __shfl_xor(q, 4); q += __shfl_xor(q, 8);
                const float mean = s * (1.f / 64.f);
                const float var = q * (1.f / 64.f) - mean * mean;
                const float rs = rsqrtf(var + EPS_);
                const int m = m0 + wm + mt * 16 + lg * 4 + r;
                const int bb = m >> 13, ll = m & 8191;
                ushort* row = Oh + ((size_t)(bb * H_ + h) * L_ + ll) * KVS_;
                row[1 + 0 * 16 + lm] = f2b((v0 - mean) * rs * gg[0] + bb2[0]);
                row[1 + 1 * 16 + lm] = f2b((v1 - mean) * rs * gg[1] + bb2[1]);
                row[1 + 2 * 16 + lm] = f2b((v2 - mean) * rs * gg[2] + bb2[2]);
                row[1 + 3 * 16 + lm] = f2b((v3 - mean) * rs * gg[3] + bb2[3]);
                if (lm == 15) row[0] = f2b(pos[m]);
                else          row[F_ + lm] = 0;   // cols 65..79 zero
            }
        }
    }
}

// ---------------- K3: attn accumulation: sum_l K[l][d]*V[l][e] ----------------
__global__ __launch_bounds__(256)
void attn_accum(const ushort* __restrict__ Kh, const ushort* __restrict__ Vh,
                float* __restrict__ attn_acc)
{
    const int s = blockIdx.x;   // 512-l slice, 0..15
    const int h = blockIdx.y;
    const int b = blockIdx.z;
    const int t = threadIdx.x;

    __shared__ __align__(16) float Ks[64][84];
    __shared__ __align__(16) float Vs[64][84];

    const size_t base = ((size_t)(b * H_ + h) * L_ + s * 512) * KVS_;

    float acc[5][5];
#pragma unroll
    for (int i = 0; i < 5; ++i)
#pragma unroll
        for (int j = 0; j < 5; ++j) acc[i][j] = 0.f;

    const int dg = t / 13, eg = t % 13;
    const bool act = (t < 169);
    const int d0 = dg * 5, e0 = eg * 5;

    for (int c = 0; c < 8; ++c) {
#pragma unroll
        for (int i = 0; i < 3; ++i) {
            const int slot = t + i * 256;
            if (slot < 640) {
                const int r = slot / 10;
                const int cc = (slot - r * 10) * 8;
                const size_t g = base + (size_t)(c * 64 + r) * KVS_ + cc;
                const short8 kv = *(const short8*)(const void*)&Kh[g];
                const short8 vv = *(const short8*)(const void*)&Vh[g];
                float* kd = &Ks[r][cc];
                float* vd = &Vs[r][cc];
#pragma unroll
                for (int e = 0; e < 8; ++e) {
                    kd[e] = b2f((ushort)kv[e]);
                    vd[e] = b2f((ushort)vv[e]);
                }
            }
        }
        __syncthreads();
        if (act) {
#pragma unroll 2
            for (int l = 0; l < 64; ++l) {
                float kf[5], vf[5];
#pragma unroll
                for (int i = 0; i < 5; ++i) kf[i] = Ks[l][d0 + i];
#pragma unroll
                for (int j = 0; j < 5; ++j) vf[j] = Vs[l][e0 + j];
#pragma unroll
                for (int i = 0; i < 5; ++i)
#pragma unroll
                    for (int j = 0; j < 5; ++j)
                        acc[i][j] = fmaf(kf[i], vf[j], acc[i][j]);
            }
        }
        __syncthreads();
    }

    if (act) {
        float* dst = attn_acc + (size_t)(b * H_ + h) * (F_ * F_);
#pragma unroll
        for (int i = 0; i < 5; ++i)
#pragma unroll
            for (int j = 0; j < 5; ++j)
                atomicAdd(&dst[(d0 + i) * F_ + (e0 + j)], acc[i][j]);
    }
}

// ---------------- K4: attn/L -> d_out; Gt[b][n][k] = (attn @ fcW_h^T)^T bf16 ----------------
__global__ __launch_bounds__(256)
void attn_fin_G(const float* __restrict__ attn_acc, const float* __restrict__ fcW,
                float* __restrict__ attn_out, ushort* __restrict__ Gt)
{
    const int nc = blockIdx.x;
    const int h = blockIdx.y;
    const int b = blockIdx.z;
    const int t = threadIdx.x;

    __shared__ float S[F_][F_];
    __shared__ float Wl[64][F_];

    const float inv = 1.0f / (float)L_;
    const float* __restrict__ src = attn_acc + (size_t)(b * H_ + h) * F_ * F_;
    for (int idx = t; idx < F_ * F_; idx += 256) {
        const float v = src[idx] * inv;
        S[idx / F_][idx % F_] = v;
        if (nc == 0) attn_out[(size_t)(b * H_ + h) * F_ * F_ + idx] = v;
    }
    for (int idx = t; idx < 64 * F_; idx += 256) {
        const int j = idx / F_;
        const int e = idx - j * F_;
        Wl[j][e] = fcW[(size_t)(nc * 64 + j) * CF_ + h * F_ + e];
    }
    __syncthreads();

    for (int idx = t; idx < F_ * 64; idx += 256) {
        const int d = idx >> 6;
        const int j = idx & 63;
        float g = 0.f;
#pragma unroll 5
        for (int e = 0; e < F_; ++e) g = fmaf(S[d][e], Wl[j][e], g);
        Gt[((size_t)b * 512 + nc * 64 + j) * CFP_ + h * F_ + d] = f2b(g);
    }
    if (h == 7) {
        for (int i2 = t; i2 < 64 * 24; i2 += 256) {
            const int j = i2 / 24;
            const int k = CF_ + (i2 % 24);
            Gt[((size_t)b * 512 + nc * 64 + j) * CFP_ + k] = 0;
        }
    }
}

// ---------------- K5: att_output = Qc @ Gt^T + fcb ----------------
__global__ __launch_bounds__(256, 2)
void out_mfma(const ushort* __restrict__ Qc, const ushort* __restrict__ Gt,
              const float* __restrict__ fcb, float* __restrict__ out)
{
    const int x  = blockIdx.x;
    const int m0 = (((x >> 5) << 3) + (x & 7)) * 128;
    const int n0 = ((x >> 3) & 3) * 128;
    const int b  = blockIdx.z;
    const int t  = threadIdx.x;
    const int w  = t >> 6, l = t & 63;
    const int wm = (w >> 1) * 64, wn = (w & 1) * 64;
    const int lg = l >> 4, lm = l & 15;

    __shared__ __align__(16) short sA[4096];
    __shared__ __align__(16) short sB[4096];

    f32x4 acc[4][4];
#pragma unroll
    for (int i = 0; i < 4; ++i)
#pragma unroll
        for (int j = 0; j < 4; ++j) acc[i][j] = (f32x4){0.f, 0.f, 0.f, 0.f};

    const ushort* A  = Qc + (size_t)(b * L_ + m0) * CFP_;
    const ushort* Bm = Gt + ((size_t)b * 512 + n0) * CFP_;

    const ushort* asrc0 = A + (size_t)l * CFP_ + w * 8;
    const ushort* asrc1 = A + (size_t)(64 + l) * CFP_ + w * 8;
    const ushort* bsrc0 = Bm + (size_t)l * CFP_ + w * 8;
    const ushort* bsrc1 = Bm + (size_t)(64 + l) * CFP_ + w * 8;
    short* al0 = &sA[(w * 128) * 8];
    short* al1 = &sA[(w * 128 + 64) * 8];
    short* bl0 = &sB[(w * 128) * 8];
    short* bl1 = &sB[(w * 128 + 64) * 8];

    const short* ar[4]; const short* br[4];
#pragma unroll
    for (int i = 0; i < 4; ++i) {
        ar[i] = &sA[(lg * 128 + wm + i * 16 + lm) * 8];
        br[i] = &sB[(lg * 128 + wn + i * 16 + lm) * 8];
    }

    for (int k0 = 0; k0 < CFP_; k0 += 32) {
        GLD16(asrc0 + k0, al0);
        GLD16(asrc1 + k0, al1);
        GLD16(bsrc0 + k0, bl0);
        GLD16(bsrc1 + k0, bl1);

        __syncthreads();

        short8 af[4], bfv[4];
#pragma unroll
        for (int i = 0; i < 4; ++i) {
            af[i]  = *(const short8*)ar[i];
            bfv[i] = *(const short8*)br[i];
        }
#pragma unroll
        for (int mt = 0; mt < 4; ++mt)
#pragma unroll
            for (int nt = 0; nt < 4; ++nt)
                acc[mt][nt] = __builtin_amdgcn_mfma_f32_16x16x32_bf16(
                    af[mt], bfv[nt], acc[mt][nt], 0, 0, 0);

        __syncthreads();
    }

    float bvv[4];
#pragma unroll
    for (int nt = 0; nt < 4; ++nt) bvv[nt] = fcb[n0 + wn + nt * 16 + lm];

#pragma unroll
    for (int mt = 0; mt < 4; ++mt) {
#pragma unroll
        for (int r = 0; r < 4; ++r) {
            const int row = m0 + wm + mt * 16 + lg * 4 + r;
            float* orow = out + ((size_t)b * L_ + row) * D_;
#pragma unroll
            for (int nt = 0; nt < 4; ++nt)
                orow[n0 + wn + nt * 16 + lm] = acc[mt][nt][r] + bvv[nt];
        }
    }
}

extern "C" void kernel_launch(void* const* d_in, const int* in_sizes, int n_in,
                              void* d_out, int out_size, void* d_ws, size_t ws_size,
                              hipStream_t stream)
{
    const float* query = (const float*)d_in[0];
    const float* key   = (const float*)d_in[1];
    const float* value = (const float*)d_in[2];
    const float* pos   = (const float*)d_in[3];
    const float* Wq    = (const float*)d_in[4];
    const float* bq    = (const float*)d_in[5];
    const float* Wk    = (const float*)d_in[6];
    const float* bk    = (const float*)d_in[7];
    const float* Wv    = (const float*)d_in[8];
    const float* bv    = (const float*)d_in[9];
    const float* gK    = (const float*)d_in[10];
    const float* betaK = (const float*)d_in[11];
    const float* gV    = (const float*)d_in[12];
    const float* betaV = (const float*)d_in[13];
    const float* fcW   = (const float*)d_in[14];
    const float* fcb   = (const float*)d_in[15];

    char* ws = (char*)d_ws;
    ushort* Qc       = (ushort*)(ws + 0);            // [32768][544] bf16
    ushort* Kh       = (ushort*)(ws + 35651584);     // [4][8][8192][80] bf16
    ushort* Vh       = (ushort*)(ws + 77594624);     // [4][8][8192][80] bf16
    ushort* Wb       = (ushort*)(ws + 119537664);    // [3][512][512] bf16
    float*  attn_acc = (float*) (ws + 121110528);    // [4][8][65][65] fp32
    ushort* Gt       = (ushort*)(ws + 121651328);    // [4][512][544] bf16

    float* att_out  = (float*)d_out;                 // [4][8192][512]
    float* attn_out = att_out + 16777216;            // [4][8][65][65]

    hipMemsetAsync(attn_acc, 0, (size_t)135200 * sizeof(float), stream);

    cast_w<<<dim3(768), 256, 0, stream>>>(Wq, Wk, Wv, Wb);

    proj_mfma<<<dim3(1024, 3), 256, 0, stream>>>(
        query, key, value, Wb, bq, bk, bv, pos,
        gK, betaK, gV, betaV, Qc, Kh, Vh);

    attn_accum<<<dim3(16, 8, 4), 256, 0, stream>>>(Kh, Vh, attn_acc);

    attn_fin_G<<<dim3(8, 8, 4), 256, 0, stream>>>(attn_acc, fcW, attn_out, Gt);

    out_mfma<<<dim3(256, 1, 4), 256, 0, stream>>>(Qc, Gt, fcb, att_out);
}